// Round 1
// 348.418 us; speedup vs baseline: 1.1284x; 1.1284x over previous
//
#include <hip/hip_runtime.h>
#include <hip/hip_fp16.h>
#include <math.h>

#define HW 65536            // 256*256
#define PITCH 272           // padded fp16 conv plane: 7+256+9 cols
#define PLANE (PITCH * PITCH)  // 73984 fp16 elements per (b,c,s) plane

typedef float v2f __attribute__((ext_vector_type(2), aligned(8)));
typedef _Float16 h2 __attribute__((ext_vector_type(2)));

// ---------- helpers ----------
__device__ __forceinline__ h2 uh(unsigned u) { return __builtin_bit_cast(h2, u); }
// aligned pair load (even element index)
__device__ __forceinline__ h2 lda(const ushort* p) { return *(const h2*)(const void*)p; }
// unaligned pair load (odd element index): two aligned dwords + merge
__device__ __forceinline__ h2 ldu(const ushort* p) {
    unsigned lo = *(const unsigned*)(const void*)(p - 1);
    unsigned hi = *(const unsigned*)(const void*)(p + 1);
    unsigned r = (hi << 16) | (lo >> 16);   // v_alignbit_b32
    return __builtin_bit_cast(h2, r);
}

#define CEH(a, b) { h2 _t = __builtin_elementwise_min(a, b); \
                    b = __builtin_elementwise_max(a, b); a = _t; }

__device__ __forceinline__ void sort8_h2(h2* v) {
    CEH(v[0], v[1]); CEH(v[2], v[3]); CEH(v[4], v[5]); CEH(v[6], v[7]);
    CEH(v[0], v[2]); CEH(v[1], v[3]); CEH(v[4], v[6]); CEH(v[5], v[7]);
    CEH(v[1], v[2]); CEH(v[5], v[6]); CEH(v[0], v[4]); CEH(v[3], v[7]);
    CEH(v[1], v[5]); CEH(v[2], v[6]);
    CEH(v[1], v[4]); CEH(v[3], v[6]);
    CEH(v[2], v[4]); CEH(v[3], v[5]);
    CEH(v[3], v[4]);
}
__device__ __forceinline__ void sort4_h2(h2* v) {
    CEH(v[0], v[1]); CEH(v[2], v[3]); CEH(v[0], v[2]); CEH(v[1], v[3]); CEH(v[1], v[2]);
}

// ---------------- K0: pack per-(c,i) weights as fp16 {w,w} u32 pairs ----------------
// layout: wtab[(c*4+i)*16 + j]: j0..2 = l1w[0..2], j3 = 2*l1w[3], j4 = l1b,
//         j5..12 = l2w[0..7], j13 = l2b, j14..15 pad.  wtab[1024 + c*4 + k] = bw.
__global__ __launch_bounds__(256) void k_pack(const float* __restrict__ l1w,
                                              const float* __restrict__ l1b,
                                              const float* __restrict__ l2w,
                                              const float* __restrict__ l2b,
                                              const float* __restrict__ bw,
                                              unsigned* __restrict__ wtab) {
    for (int t = threadIdx.x; t < 1088; t += 256) {
        float v = 0.f;
        if (t < 1024) {
            int c = t >> 6, i = (t >> 4) & 3, j = t & 15;
            if (j < 3)        v = l1w[i * 64 + c * 4 + j];
            else if (j == 3)  v = 2.f * l1w[i * 64 + c * 4 + 3];
            else if (j == 4)  v = l1b[i * 16 + c];
            else if (j < 13)  v = l2w[i * 128 + c * 8 + (j - 5)];
            else if (j == 13) v = l2b[i * 16 + c];
        } else {
            v = bw[t - 1024];
        }
        unsigned hs = (unsigned)__half_as_ushort(__float2half(v));
        wtab[t] = hs * 0x10001u;
    }
}

// ---------------- K1: in_conv 1x1, 64 -> 16, 2-px packed, LDS weights, fp16 out ----------------
__global__ __launch_bounds__(256) void k_inconv(const float* __restrict__ cen,
                                                const float* __restrict__ w,
                                                const float* __restrict__ bias,
                                                __half* __restrict__ xh) {
    __shared__ float wl[1040];   // transposed weights wl[i*16+o] = w[o*64+i], + bias
    int tid = threadIdx.x;
    for (int t = tid; t < 1024; t += 256) wl[t] = w[(t & 15) * 64 + (t >> 4)];
    if (tid < 16) wl[1024 + tid] = bias[tid];
    __syncthreads();

    int pr = blockIdx.x * 256 + tid;      // pair index, 0..262143
    int b_ = pr >> 15;
    int hw = (pr & 32767) * 2;
    const float* src = cen + (size_t)(b_ * 64) * HW + hw;

    v2f acc[16];
#pragma unroll
    for (int o = 0; o < 16; o++) { float bv = wl[1024 + o]; v2f t = {bv, bv}; acc[o] = t; }

#pragma unroll 4
    for (int i = 0; i < 64; i++) {
        v2f xv = *(const v2f*)(src + (size_t)i * HW);
        const float4* wq = (const float4*)&wl[i * 16];   // uniform -> ds broadcast
#pragma unroll
        for (int g = 0; g < 4; g++) {
            float4 f = wq[g];
            acc[g * 4 + 0] += xv * f.x;
            acc[g * 4 + 1] += xv * f.y;
            acc[g * 4 + 2] += xv * f.z;
            acc[g * 4 + 3] += xv * f.w;
        }
    }
    __half* dst = xh + (size_t)(b_ * 16) * HW + hw;
#pragma unroll
    for (int o = 0; o < 16; o++)
        *(__half2*)(dst + (size_t)o * HW) = __floats2half2_rn(acc[o].x, acc[o].y);
}

// ---------------- K2: 4 depthwise convs -> zero-guarded padded fp16 planes ----------------
// conv[(plane*4+i)][py][px], py/px padded coords (image = padded-7); guards zeroed.
__global__ __launch_bounds__(256) void k_dw(const __half* __restrict__ xh,
    const float* __restrict__ dw_w1, const float* __restrict__ dw_b1,
    const float* __restrict__ dw_w3, const float* __restrict__ dw_b3,
    const float* __restrict__ dw_w5, const float* __restrict__ dw_b5,
    const float* __restrict__ dw_w7, const float* __restrict__ dw_b7,
    __half* __restrict__ conv) {
    const int plane = blockIdx.y;          // b*16 + c
    const int c     = plane & 15;
    const int P0    = (blockIdx.x >> 2) * 68;   // padded row origin (4x68 = 272)
    const int Q0    = (blockIdx.x & 3) * 68;    // padded col origin
    const int tid   = threadIdx.x;

    __shared__ float lx[74 * 76];          // x tile: image rows/cols P0-10..P0+63
    const __half* xp = xh + (size_t)plane * HW;

    for (int t = tid; t < 74 * 74; t += 256) {
        int r = t / 74, cc = t - r * 74;
        int gy = P0 - 10 + r, gx = Q0 - 10 + cc;
        float v = 0.f;
        if ((unsigned)gy < 256u && (unsigned)gx < 256u) v = __half2float(xp[gy * 256 + gx]);
        lx[r * 76 + cc] = v;
    }
    __syncthreads();

    const float* W7 = dw_w7 + c * 49;
    const float* W5 = dw_w5 + c * 25;
    const float* W3 = dw_w3 + c * 9;
    const float  W1 = dw_w1[c];
    const float  B1 = dw_b1[c], B3 = dw_b3[c], B5 = dw_b5[c], B7 = dw_b7[c];

    for (int u = tid; u < 68 * 34; u += 256) {   // 68 rows x 34 col-pairs of the padded tile
        int row = u / 34;
        int pc0 = (u - row * 34) * 2;
        v2f c7v = {0, 0}, c5v = {0, 0}, c3v = {0, 0}, c1v = {0, 0};
#pragma unroll
        for (int a = 0; a < 7; a++) {
            const float* rp = &lx[(row + a) * 76 + pc0];
            v2f q0 = *(const v2f*)rp;
            v2f q1 = *(const v2f*)(rp + 2);
            v2f q2 = *(const v2f*)(rp + 4);
            v2f q3 = *(const v2f*)(rp + 6);
            float v8 = rp[8];
            float v[9] = {q0.x, q0.y, q1.x, q1.y, q2.x, q2.y, q3.x, q3.y, v8};
#pragma unroll
            for (int bb = 0; bb < 7; bb++) {
                v2f vv = {v[bb], v[bb + 1]};
                c7v += vv * W7[a * 7 + bb];
            }
            if (a >= 1 && a <= 5) {
#pragma unroll
                for (int bb = 0; bb < 5; bb++) {
                    v2f vv = {v[bb + 1], v[bb + 2]};
                    c5v += vv * W5[(a - 1) * 5 + bb];
                }
            }
            if (a >= 2 && a <= 4) {
#pragma unroll
                for (int bb = 0; bb < 3; bb++) {
                    v2f vv = {v[bb + 2], v[bb + 3]};
                    c3v += vv * W3[(a - 2) * 3 + bb];
                }
            }
            if (a == 3) {
                v2f vv = {v[3], v[4]};
                c1v = vv * W1;
            }
        }
        int py = P0 + row, px = Q0 + pc0;
        int iy = py - 7, ix = px - 7;
        bool rin = (unsigned)iy < 256u;
        bool in0 = rin && (unsigned)ix < 256u;
        bool in1 = rin && (unsigned)(ix + 1) < 256u;
        size_t o = (size_t)(plane * 4) * PLANE + (size_t)py * PITCH + px;
        *(__half2*)&conv[o]              = __floats2half2_rn(in0 ? c1v.x + B1 : 0.f, in1 ? c1v.y + B1 : 0.f);
        *(__half2*)&conv[o + PLANE]      = __floats2half2_rn(in0 ? c3v.x + B3 : 0.f, in1 ? c3v.y + B3 : 0.f);
        *(__half2*)&conv[o + 2 * PLANE]  = __floats2half2_rn(in0 ? c5v.x + B5 : 0.f, in1 ? c5v.y + B5 : 0.f);
        *(__half2*)&conv[o + 3 * PLANE]  = __floats2half2_rn(in0 ? c7v.x + B7 : 0.f, in1 ? c7v.y + B7 : 0.f);
    }
}

// ---------------- K3: machinery, all-fp16 packed, LDS-free, fused tail ----------------
__global__ __launch_bounds__(256) void k_mach(const __half* __restrict__ conv,
                                              const unsigned* __restrict__ wtab,
                                              const float* __restrict__ bns,
                                              const float* __restrict__ bnb,
                                              const float* __restrict__ fw,
                                              const float* __restrict__ fb,
                                              float* __restrict__ out) {
    const int b_ = blockIdx.y;                       // 0..7
    const int pr = blockIdx.x * 256 + threadIdx.x;   // pixel-pair in image, 0..32767
    const int gy = pr >> 7, gx = (pr & 127) * 2;
    const int e0 = (gy + 7) * PITCH + (gx + 7);      // center element (odd col)
    const ushort* cb = (const ushort*)conv + (size_t)(b_ * 64) * PLANE + e0;

    float fyx = fb[0], fyy = fb[0];

    for (int c = 0; c < 16; c++) {
        const ushort* cvp = cb + (size_t)(c * 4) * PLANE;
        h2 bh[4];
#pragma unroll
        for (int i = 0; i < 4; i++) {
            const int s = 1 + 2 * i;
            const ushort* pb = cvp + (size_t)i * PLANE;
            // 9 neighborhood pair-loads, compile-time immediate offsets
            h2 ctr = ldu(pb);
            h2 n0 = lda(pb - s * PITCH - s);
            h2 n1 = ldu(pb - s * PITCH);
            h2 n2 = lda(pb - s * PITCH + s);
            h2 n3 = lda(pb + s);
            h2 n4 = lda(pb + s * PITCH + s);
            h2 n5 = ldu(pb + s * PITCH);
            h2 n6 = lda(pb + s * PITCH - s);
            h2 n7 = lda(pb - s);

            h2 T[8];
            T[0] = ctr - n0; T[1] = ctr - n1; T[2] = ctr - n2; T[3] = ctr - n3;
            T[4] = ctr - n4; T[5] = ctr - n5; T[6] = ctr - n6; T[7] = ctr - n7;
            h2 S[4];
#pragma unroll
            for (int k = 0; k < 4; k++) S[k] = T[k] + T[k + 4];

            const unsigned* wt = wtab + ((c << 2) + i) * 16;   // uniform -> s_load
            h2 w10 = uh(wt[0]), w11 = uh(wt[1]), w12 = uh(wt[2]);
            h2 w13x2 = uh(wt[3]), bb1 = uh(wt[4]);

            h2 R[4];
#pragma unroll
            for (int m = 0; m < 4; m++) {
                h2 r = S[(m + 2) & 3] * w12 + bb1;
                r = S[(m + 3) & 3] * w11 + r;
                r = S[(m + 1) & 3] * w10 + r;
                R[m] = r;
            }
            h2 h8[8];
#pragma unroll
            for (int k = 0; k < 8; k++)
                h8[k] = (T[(k + 4) & 7] * w13x2 + R[k & 3]) * T[k];
            sort8_h2(h8);

            h2 acc = uh(wt[13]);
#pragma unroll
            for (int k = 0; k < 8; k++) acc += h8[k] * uh(wt[5 + k]);
            bh[i] = acc;
        }
        sort4_h2(bh);
        h2 yv = bh[0] * uh(wtab[1024 + (c << 2)]);
#pragma unroll
        for (int k = 1; k < 4; k++) yv = bh[k] * uh(wtab[1024 + (c << 2) + k]) + yv;

        float zx = fmaf((float)yv.x, bns[c], bnb[c]);
        float zy = fmaf((float)yv.y, bns[c], bnb[c]);
        float sx = zx / (1.f + __expf(-zx));
        float sy = zy / (1.f + __expf(-zy));
        fyx = fmaf(sx, fw[c], fyx);
        fyy = fmaf(sy, fw[c], fyy);
    }
    float2 r;
    r.x = 1.f / (1.f + __expf(-fyx));
    r.y = 1.f / (1.f + __expf(-fyy));
    *(float2*)&out[((long)b_ << 16) + pr * 2] = r;
}

extern "C" void kernel_launch(void* const* d_in, const int* in_sizes, int n_in,
                              void* d_out, int out_size, void* d_ws, size_t ws_size,
                              hipStream_t stream) {
    (void)in_sizes; (void)n_in; (void)out_size; (void)ws_size;
    const float* cen   = (const float*)d_in[0];
    // d_in[1] = mas (unused by the reference)
    const float* in_w  = (const float*)d_in[2];
    const float* in_b  = (const float*)d_in[3];
    const float* dw_w1 = (const float*)d_in[4];
    const float* dw_b1 = (const float*)d_in[5];
    const float* dw_w3 = (const float*)d_in[6];
    const float* dw_b3 = (const float*)d_in[7];
    const float* dw_w5 = (const float*)d_in[8];
    const float* dw_b5 = (const float*)d_in[9];
    const float* dw_w7 = (const float*)d_in[10];
    const float* dw_b7 = (const float*)d_in[11];
    const float* l1w   = (const float*)d_in[12];
    const float* l1b   = (const float*)d_in[13];
    const float* l2w   = (const float*)d_in[14];
    const float* l2b   = (const float*)d_in[15];
    const float* bw    = (const float*)d_in[16];
    const float* bns   = (const float*)d_in[17];
    const float* bnb   = (const float*)d_in[18];
    const float* fw    = (const float*)d_in[19];
    const float* fb    = (const float*)d_in[20];

    // workspace: xh (16.78 MB) | conv (75.76 MB) | wtab (4.3 KB)  = 92.5 MB total
    __half*   xh   = (__half*)d_ws;
    __half*   conv = (__half*)((char*)d_ws + (size_t)16777216);
    unsigned* wtab = (unsigned*)((char*)d_ws + (size_t)16777216 + (size_t)75759616);
    float*    out  = (float*)d_out;

    k_pack<<<1, 256, 0, stream>>>(l1w, l1b, l2w, l2b, bw, wtab);
    k_inconv<<<1024, 256, 0, stream>>>(cen, in_w, in_b, xh);
    k_dw<<<dim3(16, 128), 256, 0, stream>>>(xh, dw_w1, dw_b1, dw_w3, dw_b3,
                                            dw_w5, dw_b5, dw_w7, dw_b7, conv);
    k_mach<<<dim3(128, 8), 256, 0, stream>>>(conv, wtab, bns, bnb, fw, fb, out);
}